// Round 7
// baseline (173.525 us; speedup 1.0000x reference)
//
#include <hip/hip_runtime.h>
#include <math.h>

constexpr int NN = 4;    // batch
constexpr int CC = 128;  // channels

typedef unsigned short u16;
typedef short bfrag __attribute__((ext_vector_type(8)));   // 8 bf16
typedef float facc  __attribute__((ext_vector_type(4)));   // 4 f32 acc

__device__ __forceinline__ float bf2f(u16 v) {
    unsigned u = ((unsigned)v) << 16; float f; __builtin_memcpy(&f, &u, 4); return f;
}
__device__ __forceinline__ u16 f2bf(float f) {
    unsigned u; __builtin_memcpy(&u, &f, 4);
    unsigned r = u + 0x7FFFu + ((u >> 16) & 1u);
    return (u16)(r >> 16);
}

typedef const __attribute__((address_space(1))) unsigned int gu32;
typedef __attribute__((address_space(3))) unsigned int lu32;
__device__ __forceinline__ void gload16(const u16* g, u16* l) {
    __builtin_amdgcn_global_load_lds((gu32*)g, (lu32*)l, 16, 0, 0);
}

// =====================================================================
// Halo-LDS 3x3 conv GEMM (unchanged, verified R5/R6).
// =====================================================================
template<int WM, int WN, int MR, int NR, int NOB, int EPI>
__global__ __launch_bounds__(512)
void gconv_h(const u16* __restrict__ A, const u16* __restrict__ Wp,
             const float* __restrict__ bias, void* __restrict__ Out,
             int H, int W, int npb)
{
    constexpr int HALOW = 68;
    __shared__ __align__(16) u16 halo[4 * HALOW * 128];    // 69632 B

    const int Hp = H + 2, Wq = W + 2, HW = H * W;
    const int tid = threadIdx.x, lane = tid & 63, wv = tid >> 6;
    const int wn = wv % WN, wm = wv / WN;
    const int colc = lane & 15, kg = lane >> 4;
    const int n = blockIdx.x / npb;
    const int pib = (blockIdx.x - n * npb) * 64;
    const int ymin = pib / W;

    {
        const u16* Abase = A + (size_t)n * Hp * Wq * 128;
        for (int c = wv; c < 4 * HALOW / 4; c += 8) {
            int o = c * 512 + lane * 8;
            int r = o / (HALOW * 128);
            int e = o - r * (HALOW * 128);
            int x = e >> 7;
            int g = (e >> 3) & 15;
            int xs = x < Wq ? x : Wq - 1;
            int pr = ymin + r; if (pr > Hp - 1) pr = Hp - 1;
            const u16* src = Abase + ((size_t)pr * Wq + xs) * 128 + (g ^ (x & 7)) * 8;
            gload16(src, &halo[c * 512]);
        }
    }
    __syncthreads();

    int dyr[MR], axr[MR];
#pragma unroll
    for (int r = 0; r < MR; ++r) {
        int m = wm * (MR * 16) + r * 16 + colc;
        int pixl = pib + m; if (pixl > HW - 1) pixl = HW - 1;
        int y = pixl / W;
        dyr[r] = y - ymin; axr[r] = pixl - y * W;
    }

    auto wfrag = [&](int tap, int cc, int q) -> const bfrag* {
        return (const bfrag*)(Wp + (size_t)tap * (NOB * 2048)
                              + ((cc * NOB + wn * NR + q) * 64 + lane) * 8);
    };

    bfrag bc[4][NR];
#pragma unroll
    for (int cc = 0; cc < 4; ++cc)
#pragma unroll
        for (int q = 0; q < NR; ++q) bc[cc][q] = *wfrag(0, cc, q);

    facc acc[MR][NR];
#pragma unroll
    for (int r = 0; r < MR; ++r)
#pragma unroll
        for (int q = 0; q < NR; ++q) acc[r][q] = (facc){0.f, 0.f, 0.f, 0.f};

#pragma unroll 1
    for (int t = 0; t < 9; ++t) {
        int ty = t / 3, tx = t - ty * 3;
        bfrag bn_[4][NR];
        if (t < 8) {
#pragma unroll
            for (int cc = 0; cc < 4; ++cc)
#pragma unroll
                for (int q = 0; q < NR; ++q) bn_[cc][q] = *wfrag(t + 1, cc, q);
        }
#pragma unroll
        for (int cc = 0; cc < 4; ++cc) {
            bfrag a[MR];
#pragma unroll
            for (int r = 0; r < MR; ++r) {
                int xx = axr[r] + tx;
                a[r] = *(const bfrag*)&halo[((dyr[r] + ty) * HALOW + xx) * 128
                                            + ((cc * 4 + kg) ^ (xx & 7)) * 8];
            }
#pragma unroll
            for (int r = 0; r < MR; ++r)
#pragma unroll
                for (int q = 0; q < NR; ++q)
                    acc[r][q] = __builtin_amdgcn_mfma_f32_16x16x32_bf16(a[r], bc[cc][q], acc[r][q], 0, 0, 0);
        }
        if (t < 8) {
#pragma unroll
            for (int cc = 0; cc < 4; ++cc)
#pragma unroll
                for (int q = 0; q < NR; ++q) bc[cc][q] = bn_[cc][q];
        }
    }

#pragma unroll
    for (int r = 0; r < MR; ++r) {
#pragma unroll
        for (int j = 0; j < 4; ++j) {
            int m = wm * (MR * 16) + r * 16 + kg * 4 + j;
            int pixl = pib + m;
            if (pixl >= HW) continue;
#pragma unroll
            for (int q = 0; q < NR; ++q) {
                int oc = wn * (NR * 16) + q * 16 + colc;
                float val = acc[r][q][j] + bias[oc];
                if constexpr (EPI == 0) {
                    val = fmaxf(val, 0.f);
                    int y = pixl / W, x = pixl - y * W;
                    ((u16*)Out)[((size_t)(n * Hp + y + 1) * Wq + x + 1) * 128 + oc] = f2bf(val);
                } else {
                    if (oc >= 18) val = 2.f / (1.f + expf(-val));
                    ((float*)Out)[((size_t)n * HW + pixl) * 32 + oc] = val;
                }
            }
        }
    }
}

// =====================================================================
// 2D-tiled LDS bilinear sampler. Block = 8x8 pixel tile of one image.
// Stage 12x12 halo (granule-major [gr][row][col], coalesced gload16)
// + OM slice (granule-transposed) ONCE; one barrier; then 576 (pix,tap)
// tasks gather purely from LDS (global fallback only if |off| pushes a
// corner outside the window - rare, exact). Writes Acol[pix][tap*128+c].
// =====================================================================
__global__ __launch_bounds__(256)
void sample2_k(const u16* __restrict__ Hb, const float* __restrict__ OM,
               u16* __restrict__ Acol, int H, int W, int tw, int th)
{
    __shared__ __align__(16) u16 halo[16 * 144 * 8];   // 36864 B
    __shared__ __align__(16) float oml[2048];          // 8192 B, [q8][p][4f]

    const int Hp = H + 2, Wq = W + 2, HW = H * W;
    const int tid = threadIdx.x, wv = tid >> 6, lane = tid & 63;
    int bt = blockIdx.x;
    int n = bt / (tw * th); int rt = bt - n * (tw * th);
    int ty0 = (rt / tw) * 8, tx0 = (rt - (rt / tw) * tw) * 8;

    const u16* Hbase = Hb + (size_t)n * Hp * Wq * 128;

    // ---- stage halo: 2304 granules of 16B, [gr][row][col]
#pragma unroll
    for (int c = 0; c < 9; ++c) {
        int g = c * 256 + tid;
        int gr = g / 144, rem = g - gr * 144;
        int row = rem / 12, col = rem - row * 12;
        int gy = min(max(ty0 - 2 + row, 0), H - 1);
        int gx = min(max(tx0 - 2 + col, 0), W - 1);
        gload16(Hbase + ((size_t)(gy + 1) * Wq + gx + 1) * 128 + gr * 8,
                &halo[(c * 256 + wv * 64) * 8]);
    }
    // ---- stage om: 512 granules, [q8][p]
#pragma unroll
    for (int c = 0; c < 2; ++c) {
        int g = c * 256 + tid;
        int q8 = g >> 6, p = g & 63;
        int gy = min(ty0 + (p >> 3), H - 1);
        int gx = min(tx0 + (p & 7), W - 1);
        gload16((const u16*)(OM + ((size_t)n * HW + gy * W + gx) * 32) + q8 * 8,
                (u16*)oml + (c * 256 + wv * 64) * 8);
    }
    __syncthreads();

    const int p = lane, py = p >> 3, px = p & 7;
    const int y = ty0 + py, x = tx0 + px;
    const bool valid = (y < H) && (x < W);
    u16* arow = Acol + ((size_t)n * HW + min(y, H - 1) * W + min(x, W - 1)) * 1152;

#pragma unroll 1
    for (int k = wv; k < 9; k += 4) {
        if (!valid) continue;
        int gk = k >> 1, ik = (k & 1) * 2;
        float dy = oml[(gk * 64 + p) * 4 + ik];
        float dx = oml[(gk * 64 + p) * 4 + ik + 1];
        int gm = (72 + 4 * k) >> 4, im = ((72 + 4 * k) >> 2) & 3;
        float mm = oml[(gm * 64 + p) * 4 + im];

        float pyf = (float)y - 1.f + (float)(k / 3) + dy;
        float pxf = (float)x - 1.f + (float)(k % 3) + dx;
        float fy = floorf(pyf), fx = floorf(pxf);
        int y0 = (int)fy, x0 = (int)fx;
        float wy = pyf - fy, wx = pxf - fx;
        bool y0v = (y0 >= 0) && (y0 < H), y1v = (y0 >= -1) && (y0 < H - 1);
        bool x0v = (x0 >= 0) && (x0 < W), x1v = (x0 >= -1) && (x0 < W - 1);
        int yc0 = min(max(y0, 0), H - 1), yc1 = min(max(y0 + 1, 0), H - 1);
        int xc0 = min(max(x0, 0), W - 1), xc1 = min(max(x0 + 1, 0), W - 1);
        float w00 = (1.f - wy) * (1.f - wx) * ((y0v && x0v) ? mm : 0.f);
        float w01 = (1.f - wy) * wx         * ((y0v && x1v) ? mm : 0.f);
        float w10 = wy * (1.f - wx)         * ((y1v && x0v) ? mm : 0.f);
        float w11 = wy * wx                 * ((y1v && x1v) ? mm : 0.f);

        int ry0 = yc0 - (ty0 - 2), ry1 = yc1 - (ty0 - 2);
        int rx0 = xc0 - (tx0 - 2), rx1 = xc1 - (tx0 - 2);
        bool allin = (unsigned)ry0 < 12u && (unsigned)ry1 < 12u
                  && (unsigned)rx0 < 12u && (unsigned)rx1 < 12u;
        u16* dst = arow + k * 128;

        if (allin) {
            int a00 = ((ry0 * 12 + rx0)) * 8, a01 = ((ry0 * 12 + rx1)) * 8;
            int a10 = ((ry1 * 12 + rx0)) * 8, a11 = ((ry1 * 12 + rx1)) * 8;
#pragma unroll
            for (int gr = 0; gr < 16; ++gr) {
                int gb = gr * 144 * 8;
                bfrag c00 = *(const bfrag*)&halo[gb + a00];
                bfrag c01 = *(const bfrag*)&halo[gb + a01];
                bfrag c10 = *(const bfrag*)&halo[gb + a10];
                bfrag c11 = *(const bfrag*)&halo[gb + a11];
                bfrag o;
#pragma unroll
                for (int j = 0; j < 8; ++j) {
                    float f = w00 * bf2f((u16)c00[j]) + w01 * bf2f((u16)c01[j])
                            + w10 * bf2f((u16)c10[j]) + w11 * bf2f((u16)c11[j]);
                    o[j] = (short)f2bf(f);
                }
                *(bfrag*)(dst + gr * 8) = o;
            }
        } else {
            const u16* g00 = Hbase + ((size_t)(yc0 + 1) * Wq + xc0 + 1) * 128;
            const u16* g01 = Hbase + ((size_t)(yc0 + 1) * Wq + xc1 + 1) * 128;
            const u16* g10 = Hbase + ((size_t)(yc1 + 1) * Wq + xc0 + 1) * 128;
            const u16* g11 = Hbase + ((size_t)(yc1 + 1) * Wq + xc1 + 1) * 128;
#pragma unroll
            for (int gr = 0; gr < 16; ++gr) {
                bfrag c00 = *(const bfrag*)(g00 + gr * 8);
                bfrag c01 = *(const bfrag*)(g01 + gr * 8);
                bfrag c10 = *(const bfrag*)(g10 + gr * 8);
                bfrag c11 = *(const bfrag*)(g11 + gr * 8);
                bfrag o;
#pragma unroll
                for (int j = 0; j < 8; ++j) {
                    float f = w00 * bf2f((u16)c00[j]) + w01 * bf2f((u16)c01[j])
                            + w10 * bf2f((u16)c10[j]) + w11 * bf2f((u16)c11[j]);
                    o[j] = (short)f2bf(f);
                }
                *(bfrag*)(dst + gr * 8) = o;
            }
        }
    }
}

// =====================================================================
// Dense deform GEMM (unchanged, verified R6): M=NHW, N=128, K=10x128.
// =====================================================================
__global__ __launch_bounds__(512)
void dgemm_k(const u16* __restrict__ Acol, const u16* __restrict__ Xp,
             const u16* __restrict__ Wp, const float* __restrict__ biasC,
             float* __restrict__ T, int H, int W)
{
    __shared__ __align__(16) u16 As[2][64 * 128];          // 32768 B

    const int Hp = H + 2, Wq = W + 2, HW = H * W, NHW = NN * HW;
    const int tid = threadIdx.x, lane = tid & 63, wv = tid >> 6;
    const int wn = wv & 3, wm = wv >> 2;
    const int colc = lane & 15, kg = lane >> 4;
    const int m_base = blockIdx.x * 64;

    const int sg = tid & 15, srow = tid >> 4;
    size_t soffA[2], soffX[2];
#pragma unroll
    for (int pass = 0; pass < 2; ++pass) {
        int r = pass * 32 + srow;
        int pix = m_base + r; if (pix > NHW - 1) pix = NHW - 1;
        int gz = (sg ^ (r & 7)) * 8;
        soffA[pass] = (size_t)pix * 1152 + gz;
        int n = pix / HW, rr2 = pix - n * HW, y = rr2 / W, x = rr2 - y * W;
        soffX[pass] = ((size_t)(n * Hp + y + 1) * Wq + x + 1) * 128 + gz;
    }

    auto stage = [&](int buf, int tap) {
        if (tap < 9) {
            gload16(Acol + soffA[0] + tap * 128, &As[buf][wv * 512]);
            gload16(Acol + soffA[1] + tap * 128, &As[buf][4096 + wv * 512]);
        } else {
            gload16(Xp + soffX[0], &As[buf][wv * 512]);
            gload16(Xp + soffX[1], &As[buf][4096 + wv * 512]);
        }
    };
    auto wfrag = [&](int tap, int cc, int q) -> const bfrag* {
        return (const bfrag*)(Wp + (size_t)tap * 16384
                              + ((cc * 8 + wn * 2 + q) * 64 + lane) * 8);
    };

    bfrag bc[4][2];
#pragma unroll
    for (int cc = 0; cc < 4; ++cc)
#pragma unroll
        for (int q = 0; q < 2; ++q) bc[cc][q] = *wfrag(0, cc, q);

    facc acc[2][2];
#pragma unroll
    for (int r = 0; r < 2; ++r)
#pragma unroll
        for (int q = 0; q < 2; ++q) acc[r][q] = (facc){0.f, 0.f, 0.f, 0.f};

    stage(0, 0);
    __syncthreads();

#pragma unroll 1
    for (int t = 0; t < 10; ++t) {
        bfrag bn_[4][2];
        if (t < 9) {
#pragma unroll
            for (int cc = 0; cc < 4; ++cc)
#pragma unroll
                for (int q = 0; q < 2; ++q) bn_[cc][q] = *wfrag(t + 1, cc, q);
            stage((t + 1) & 1, t + 1);
        }
        const u16* as = As[t & 1];
#pragma unroll
        for (int cc = 0; cc < 4; ++cc) {
            bfrag a[2];
#pragma unroll
            for (int r = 0; r < 2; ++r) {
                int m = wm * 32 + r * 16 + colc;
                a[r] = *(const bfrag*)&as[m * 128 + ((cc * 4 + kg) ^ (m & 7)) * 8];
            }
#pragma unroll
            for (int r = 0; r < 2; ++r)
#pragma unroll
                for (int q = 0; q < 2; ++q)
                    acc[r][q] = __builtin_amdgcn_mfma_f32_16x16x32_bf16(a[r], bc[cc][q], acc[r][q], 0, 0, 0);
        }
        if (t < 9) {
#pragma unroll
            for (int cc = 0; cc < 4; ++cc)
#pragma unroll
                for (int q = 0; q < 2; ++q) bc[cc][q] = bn_[cc][q];
        }
        __syncthreads();
    }

#pragma unroll
    for (int r = 0; r < 2; ++r) {
#pragma unroll
        for (int j = 0; j < 4; ++j) {
            int pix = m_base + wm * 32 + r * 16 + kg * 4 + j;
            if (pix >= NHW) continue;
#pragma unroll
            for (int q = 0; q < 2; ++q) {
                int oc = wn * 32 + q * 16 + colc;
                T[(size_t)pix * 128 + oc] = fmaxf(acc[r][q][j] + biasC[oc], 0.f);
            }
        }
    }
}

// ---- maxpool 2x2 s1 pad1 (unchanged) -------------------------------------
template<int OUTMODE>
__global__ __launch_bounds__(256)
void pool_k(const float* __restrict__ T, void* __restrict__ Out, int H, int W)
{
    const int HW = H * W, Ho = H + 1, Wo = W + 1;
    int tot = NN * Ho * Wo * 16;
    int idx = blockIdx.x * 256 + threadIdx.x;
    if (idx >= tot) return;
    int cg = idx & 15; int t = idx >> 4;
    int ox = t % Wo; t /= Wo; int oy = t % Ho; int n = t / Ho;

    float mx[8];
#pragma unroll
    for (int j = 0; j < 8; ++j) mx[j] = -INFINITY;
#pragma unroll
    for (int d = 0; d < 2; ++d) {
        int iy = oy - 1 + d;
        if (iy < 0 || iy >= H) continue;
#pragma unroll
        for (int e = 0; e < 2; ++e) {
            int ix = ox - 1 + e;
            if (ix < 0 || ix >= W) continue;
            const float* src = T + ((size_t)(n * HW + iy * W + ix)) * 128 + cg * 8;
#pragma unroll
            for (int j = 0; j < 8; ++j) mx[j] = fmaxf(mx[j], src[j]);
        }
    }
    if constexpr (OUTMODE == 0) {
        int Hp2 = Ho + 2, Wp2 = Wo + 2;
        bfrag o;
#pragma unroll
        for (int j = 0; j < 8; ++j) o[j] = (short)f2bf(mx[j]);
        *(bfrag*)((u16*)Out + ((size_t)(n * Hp2 + oy + 1) * Wp2 + (ox + 1)) * 128 + cg * 8) = o;
    } else {
#pragma unroll
        for (int j = 0; j < 8; ++j) {
            int c = cg * 8 + j;
            ((float*)Out)[(((size_t)n * 128 + c) * Ho + oy) * Wo + ox] = mx[j];
        }
    }
}

// ---- zero the padded buffers (replaces all hipMemsetAsync) ---------------
__global__ __launch_bounds__(256)
void prep_k(u16* __restrict__ Xp0, u16* __restrict__ Xp1,
            u16* __restrict__ Hp0, u16* __restrict__ Hp1)
{
    const int G0 = (NN * 66 * 66 * 128) / 8;   // granules of 8 u16
    const int G1 = (NN * 67 * 67 * 128) / 8;
    int idx = blockIdx.x * 256 + threadIdx.x;
    bfrag z = (bfrag){0, 0, 0, 0, 0, 0, 0, 0};
    if (idx < G0) { *(bfrag*)(Xp0 + (size_t)idx * 8) = z; return; }
    idx -= G0;
    if (idx < G1) { *(bfrag*)(Xp1 + (size_t)idx * 8) = z; return; }
    idx -= G1;
    if (idx < G0) { *(bfrag*)(Hp0 + (size_t)idx * 8) = z; return; }
    idx -= G0;
    if (idx < G1) { *(bfrag*)(Hp1 + (size_t)idx * 8) = z; return; }
}

// ---- x (NCHW f32) -> padded NHWC bf16 (64x64 -> 66x66) -------------------
__global__ __launch_bounds__(256)
void x0_to_nhwc(const float* __restrict__ x0, u16* __restrict__ Xp)
{
    int idx = blockIdx.x * 256 + threadIdx.x;
    if (idx >= NN * 64 * 64 * 16) return;
    int cg = idx & 15; int t = idx >> 4;
    int x = t & 63; t >>= 6; int y = t & 63; int n = t >> 6;
    bfrag o;
#pragma unroll
    for (int j = 0; j < 8; ++j) {
        int c = cg * 8 + j;
        o[j] = (short)f2bf(x0[(((size_t)n * 128 + c) * 64 + y) * 64 + x]);
    }
    *(bfrag*)(Xp + ((size_t)(n * 66 + y + 1) * 66 + (x + 1)) * 128 + cg * 8) = o;
}

// ---- weight prep (unchanged) ---------------------------------------------
__global__ __launch_bounds__(256)
void wprep_k(const float* __restrict__ w1, const float* __restrict__ b1,
             const float* __restrict__ g1, const float* __restrict__ be1,
             const float* __restrict__ m1, const float* __restrict__ v1,
             const float* __restrict__ w_off, const float* __restrict__ b_off,
             const float* __restrict__ w_mod, const float* __restrict__ b_mod,
             const float* __restrict__ w_def, const float* __restrict__ b_def,
             const float* __restrict__ g2, const float* __restrict__ be2,
             const float* __restrict__ m2, const float* __restrict__ v2,
             const float* __restrict__ w_ds, const float* __restrict__ b_ds,
             const float* __restrict__ g3, const float* __restrict__ be3,
             const float* __restrict__ m3, const float* __restrict__ v3,
             u16* __restrict__ Wb1p, u16* __restrict__ Wbomp, u16* __restrict__ Wbdp,
             float* __restrict__ bias1f, float* __restrict__ biasOM, float* __restrict__ biasC)
{
    const int C1 = 9 * 4 * 8 * 512;   // 147456
    const int C2 = 9 * 4 * 2 * 512;   // 36864
    const int C3 = 10 * 4 * 8 * 512;  // 163840
    int idx = blockIdx.x * 256 + threadIdx.x;
    if (idx < 2 * C1) {
        int inst = idx / C1, e = idx - inst * C1;
        int j = e & 7, lane = (e >> 3) & 63, rest = e >> 9;
        int ob = rest & 7; rest >>= 3; int cc = rest & 3; int tap = rest >> 2;
        int oc = ob * 16 + (lane & 15), c = cc * 32 + (lane >> 4) * 8 + j;
        float sc = g1[inst * 128 + oc] * rsqrtf(v1[inst * 128 + oc] + 1e-5f);
        Wb1p[idx] = f2bf(sc * w1[(((size_t)inst * 128 + oc) * 128 + c) * 9 + tap]);
        return;
    }
    idx -= 2 * C1;
    if (idx < 2 * C2) {
        int inst = idx / C2, e = idx - inst * C2;
        int j = e & 7, lane = (e >> 3) & 63, rest = e >> 9;
        int ob = rest & 1; rest >>= 1; int cc = rest & 3; int tap = rest >> 2;
        int oc = ob * 16 + (lane & 15), c = cc * 32 + (lane >> 4) * 8 + j;
        float v = 0.f;
        if (oc < 18)      v = w_off[(((size_t)inst * 18 + oc) * 128 + c) * 9 + tap];
        else if (oc < 27) v = w_mod[(((size_t)inst * 9 + (oc - 18)) * 128 + c) * 9 + tap];
        Wbomp[inst * C2 + e] = f2bf(v);
        return;
    }
    idx -= 2 * C2;
    if (idx < 2 * C3) {
        int inst = idx / C3, e = idx - inst * C3;
        int j = e & 7, lane = (e >> 3) & 63, rest = e >> 9;
        int ob = rest & 7; rest >>= 3; int cc = rest & 3; int tap = rest >> 2;
        int oc = ob * 16 + (lane & 15), c = cc * 32 + (lane >> 4) * 8 + j;
        float val;
        if (tap < 9) {
            float sc2 = g2[inst * 128 + oc] * rsqrtf(v2[inst * 128 + oc] + 1e-5f);
            val = sc2 * w_def[(((size_t)inst * 128 + oc) * 128 + c) * 9 + tap];
        } else {
            float sc3 = g3[inst * 128 + oc] * rsqrtf(v3[inst * 128 + oc] + 1e-5f);
            val = sc3 * w_ds[((size_t)inst * 128 + oc) * 128 + c];
        }
        Wbdp[inst * C3 + e] = f2bf(val);
        return;
    }
    idx -= 2 * C3;
    if (idx < 2 * 288) {
        int inst = idx / 288, r = idx - inst * 288;
        if (r < 128) {
            int oc = r, o = inst * 128 + oc;
            float sc = g1[o] * rsqrtf(v1[o] + 1e-5f);
            bias1f[o] = sc * b1[o] + be1[o] - m1[o] * sc;
        } else if (r < 160) {
            int oc = r - 128;
            float v = 0.f;
            if (oc < 18)      v = b_off[inst * 18 + oc];
            else if (oc < 27) v = b_mod[inst * 9 + (oc - 18)];
            biasOM[inst * 32 + oc] = v;
        } else {
            int oc = r - 160, o = inst * 128 + oc;
            float sc2 = g2[o] * rsqrtf(v2[o] + 1e-5f);
            float sc3 = g3[o] * rsqrtf(v3[o] + 1e-5f);
            biasC[o] = sc2 * b_def[o] + (be2[o] - m2[o] * sc2)
                     + sc3 * b_ds[o] + (be3[o] - m3[o] * sc3);
        }
    }
}

extern "C" void kernel_launch(void* const* d_in, const int* in_sizes, int n_in,
                              void* d_out, int out_size, void* d_ws, size_t ws_size,
                              hipStream_t stream)
{
    const float* x0    = (const float*)d_in[0];
    const float* w1    = (const float*)d_in[1];
    const float* b1    = (const float*)d_in[2];
    const float* g1    = (const float*)d_in[3];
    const float* be1   = (const float*)d_in[4];
    const float* m1    = (const float*)d_in[5];
    const float* v1    = (const float*)d_in[6];
    const float* w_off = (const float*)d_in[7];
    const float* b_off = (const float*)d_in[8];
    const float* w_mod = (const float*)d_in[9];
    const float* b_mod = (const float*)d_in[10];
    const float* w_def = (const float*)d_in[11];
    const float* b_def = (const float*)d_in[12];
    const float* g2    = (const float*)d_in[13];
    const float* be2   = (const float*)d_in[14];
    const float* m2    = (const float*)d_in[15];
    const float* v2    = (const float*)d_in[16];
    const float* w_ds  = (const float*)d_in[17];
    const float* b_ds  = (const float*)d_in[18];
    const float* g3    = (const float*)d_in[19];
    const float* be3   = (const float*)d_in[20];
    const float* m3    = (const float*)d_in[21];
    const float* v3    = (const float*)d_in[22];

    const int C1 = 147456, C2 = 36864, C3 = 163840;
    char* wsp = (char*)d_ws;
    auto alloc = [&](size_t bytes) { char* r = wsp; wsp += (bytes + 255) & ~(size_t)255; return r; };
    const size_t szX0 = (size_t)NN * 66 * 66 * 128 * 2;
    const size_t szX1 = (size_t)NN * 67 * 67 * 128 * 2;
    u16*   Xpad0  = (u16*)alloc(szX0);
    u16*   Xpad1  = (u16*)alloc(szX1);
    u16*   Hpad0  = (u16*)alloc(szX0);
    u16*   Hpad1  = (u16*)alloc(szX1);
    float* OFFMSK = (float*)alloc((size_t)16900 * 32 * 4);
    float* T      = (float*)alloc((size_t)16900 * 128 * 4);
    u16*   Acol   = (u16*)alloc((size_t)16900 * 1152 * 2);   // im2col, 38.9 MB
    u16*   Wb1p   = (u16*)alloc((size_t)2 * C1 * 2);
    u16*   Wbomp  = (u16*)alloc((size_t)2 * C2 * 2);
    u16*   Wbdp   = (u16*)alloc((size_t)2 * C3 * 2);
    float* bias1f = (float*)alloc(2 * 128 * 4);
    float* biasOM = (float*)alloc(2 * 32 * 4);
    float* biasC  = (float*)alloc(2 * 128 * 4);

    // ---- prologue: zero pads + layout conversion + weight packing --------
    const int G0 = (NN * 66 * 66 * 128) / 8, G1 = (NN * 67 * 67 * 128) / 8;
    int ztot = 2 * G0 + 2 * G1;
    prep_k<<<(ztot + 255) / 256, 256, 0, stream>>>(Xpad0, Xpad1, Hpad0, Hpad1);
    x0_to_nhwc<<<(NN * 64 * 64 * 16 + 255) / 256, 256, 0, stream>>>(x0, Xpad0);
    int ptot = 2 * C1 + 2 * C2 + 2 * C3 + 2 * 288;
    wprep_k<<<(ptot + 255) / 256, 256, 0, stream>>>(
        w1, b1, g1, be1, m1, v1, w_off, b_off, w_mod, b_mod, w_def, b_def,
        g2, be2, m2, v2, w_ds, b_ds, g3, be3, m3, v3,
        Wb1p, Wbomp, Wbdp, bias1f, biasOM, biasC);

    const u16* curX = Xpad0;
    for (int i = 0; i < 2; ++i) {
        int H = 64 + i, W = 64 + i;
        int HW = H * W;
        int NHW = NN * HW;
        int npb = (HW + 63) / 64;
        int grid = NN * npb;
        u16* Hpad = (i == 0) ? Hpad0 : Hpad1;

        // h = relu(bn1(conv3x3(x)))
        gconv_h<2, 4, 2, 2, 8, 0><<<grid, 512, 0, stream>>>(
            curX, Wb1p + (size_t)i * C1, bias1f + i * 128, Hpad, H, W, npb);
        // off(18) + msk(9, 2*sigmoid) -> OFFMSK [pix][32]
        gconv_h<4, 2, 1, 1, 2, 1><<<grid, 512, 0, stream>>>(
            Hpad, Wbomp + (size_t)i * C2, biasOM + i * 32, OFFMSK, H, W, npb);
        // 2D-tiled LDS bilinear sample -> Acol
        int tw = (W + 7) / 8, th = (H + 7) / 8;
        sample2_k<<<NN * tw * th, 256, 0, stream>>>(Hpad, OFFMSK, Acol, H, W, tw, th);
        // dense GEMM: 9 sampled taps + residual tap from curX
        dgemm_k<<<(NHW + 63) / 64, 512, 0, stream>>>(
            Acol, curX, Wbdp + (size_t)i * C3, biasC + i * 128, T, H, W);
        // maxpool
        if (i == 0) {
            pool_k<0><<<(NN * 65 * 65 * 16 + 255) / 256, 256, 0, stream>>>(T, Xpad1, H, W);
        } else {
            pool_k<1><<<(NN * 66 * 66 * 16 + 255) / 256, 256, 0, stream>>>(T, d_out, H, W);
        }
        curX = Xpad1;
    }
}

// Round 8
// 167.934 us; speedup vs baseline: 1.0333x; 1.0333x over previous
//
#include <hip/hip_runtime.h>
#include <math.h>

constexpr int NN = 4;    // batch
constexpr int CC = 128;  // channels

typedef unsigned short u16;
typedef short bfrag __attribute__((ext_vector_type(8)));   // 8 bf16
typedef float facc  __attribute__((ext_vector_type(4)));   // 4 f32 acc

__device__ __forceinline__ float bf2f(u16 v) {
    unsigned u = ((unsigned)v) << 16; float f; __builtin_memcpy(&f, &u, 4); return f;
}
__device__ __forceinline__ u16 f2bf(float f) {
    unsigned u; __builtin_memcpy(&u, &f, 4);
    unsigned r = u + 0x7FFFu + ((u >> 16) & 1u);
    return (u16)(r >> 16);
}

typedef const __attribute__((address_space(1))) unsigned int gu32;
typedef __attribute__((address_space(3))) unsigned int lu32;
__device__ __forceinline__ void gload16(const u16* g, u16* l) {
    __builtin_amdgcn_global_load_lds((gu32*)g, (lu32*)l, 16, 0, 0);
}

// =====================================================================
// Halo-LDS 3x3 conv GEMM (unchanged, verified R5-R7).
// =====================================================================
template<int WM, int WN, int MR, int NR, int NOB, int EPI>
__global__ __launch_bounds__(512)
void gconv_h(const u16* __restrict__ A, const u16* __restrict__ Wp,
             const float* __restrict__ bias, void* __restrict__ Out,
             int H, int W, int npb)
{
    constexpr int HALOW = 68;
    __shared__ __align__(16) u16 halo[4 * HALOW * 128];    // 69632 B

    const int Hp = H + 2, Wq = W + 2, HW = H * W;
    const int tid = threadIdx.x, lane = tid & 63, wv = tid >> 6;
    const int wn = wv % WN, wm = wv / WN;
    const int colc = lane & 15, kg = lane >> 4;
    const int n = blockIdx.x / npb;
    const int pib = (blockIdx.x - n * npb) * 64;
    const int ymin = pib / W;

    {
        const u16* Abase = A + (size_t)n * Hp * Wq * 128;
        for (int c = wv; c < 4 * HALOW / 4; c += 8) {
            int o = c * 512 + lane * 8;
            int r = o / (HALOW * 128);
            int e = o - r * (HALOW * 128);
            int x = e >> 7;
            int g = (e >> 3) & 15;
            int xs = x < Wq ? x : Wq - 1;
            int pr = ymin + r; if (pr > Hp - 1) pr = Hp - 1;
            const u16* src = Abase + ((size_t)pr * Wq + xs) * 128 + (g ^ (x & 7)) * 8;
            gload16(src, &halo[c * 512]);
        }
    }
    __syncthreads();

    int dyr[MR], axr[MR];
#pragma unroll
    for (int r = 0; r < MR; ++r) {
        int m = wm * (MR * 16) + r * 16 + colc;
        int pixl = pib + m; if (pixl > HW - 1) pixl = HW - 1;
        int y = pixl / W;
        dyr[r] = y - ymin; axr[r] = pixl - y * W;
    }

    auto wfrag = [&](int tap, int cc, int q) -> const bfrag* {
        return (const bfrag*)(Wp + (size_t)tap * (NOB * 2048)
                              + ((cc * NOB + wn * NR + q) * 64 + lane) * 8);
    };

    bfrag bc[4][NR];
#pragma unroll
    for (int cc = 0; cc < 4; ++cc)
#pragma unroll
        for (int q = 0; q < NR; ++q) bc[cc][q] = *wfrag(0, cc, q);

    facc acc[MR][NR];
#pragma unroll
    for (int r = 0; r < MR; ++r)
#pragma unroll
        for (int q = 0; q < NR; ++q) acc[r][q] = (facc){0.f, 0.f, 0.f, 0.f};

#pragma unroll 1
    for (int t = 0; t < 9; ++t) {
        int ty = t / 3, tx = t - ty * 3;
        bfrag bn_[4][NR];
        if (t < 8) {
#pragma unroll
            for (int cc = 0; cc < 4; ++cc)
#pragma unroll
                for (int q = 0; q < NR; ++q) bn_[cc][q] = *wfrag(t + 1, cc, q);
        }
#pragma unroll
        for (int cc = 0; cc < 4; ++cc) {
            bfrag a[MR];
#pragma unroll
            for (int r = 0; r < MR; ++r) {
                int xx = axr[r] + tx;
                a[r] = *(const bfrag*)&halo[((dyr[r] + ty) * HALOW + xx) * 128
                                            + ((cc * 4 + kg) ^ (xx & 7)) * 8];
            }
#pragma unroll
            for (int r = 0; r < MR; ++r)
#pragma unroll
                for (int q = 0; q < NR; ++q)
                    acc[r][q] = __builtin_amdgcn_mfma_f32_16x16x32_bf16(a[r], bc[cc][q], acc[r][q], 0, 0, 0);
        }
        if (t < 8) {
#pragma unroll
            for (int cc = 0; cc < 4; ++cc)
#pragma unroll
                for (int q = 0; q < NR; ++q) bc[cc][q] = bn_[cc][q];
        }
    }

#pragma unroll
    for (int r = 0; r < MR; ++r) {
#pragma unroll
        for (int j = 0; j < 4; ++j) {
            int m = wm * (MR * 16) + r * 16 + kg * 4 + j;
            int pixl = pib + m;
            if (pixl >= HW) continue;
#pragma unroll
            for (int q = 0; q < NR; ++q) {
                int oc = wn * (NR * 16) + q * 16 + colc;
                float val = acc[r][q][j] + bias[oc];
                if constexpr (EPI == 0) {
                    val = fmaxf(val, 0.f);
                    int y = pixl / W, x = pixl - y * W;
                    ((u16*)Out)[((size_t)(n * Hp + y + 1) * Wq + x + 1) * 128 + oc] = f2bf(val);
                } else {
                    if (oc >= 18) val = 2.f / (1.f + expf(-val));
                    ((float*)Out)[((size_t)n * HW + pixl) * 32 + oc] = val;
                }
            }
        }
    }
}

// =====================================================================
// 2D-tiled LDS bilinear sampler, v3: 1024 threads = 16 waves.
// Block = 8x8 pixel tile. Stage 12x12 halo (granule-major) + OM slice
// once; one barrier; 144 (tap,granule) units, 9 per wave, balanced.
// Store COALESCED to Acol2[(tap*16+gr)*NHW + pix] (16B/pixel granule).
// Rare out-of-window corners fall back to global (exact any offset).
// =====================================================================
__global__ __launch_bounds__(1024)
void sample3_k(const u16* __restrict__ Hb, const float* __restrict__ OM,
               u16* __restrict__ Acol, int H, int W, int tw, int th)
{
    __shared__ __align__(16) u16 halo[16 * 144 * 8];   // 36864 B
    __shared__ __align__(16) float oml[2048];          // 8192 B, [q8][p][4f]

    const int Hp = H + 2, Wq = W + 2, HW = H * W, NHW = NN * HW;
    const int tid = threadIdx.x, wv = tid >> 6, lane = tid & 63;
    int bt = blockIdx.x;
    int n = bt / (tw * th); int rt = bt - n * (tw * th);
    int ty0 = (rt / tw) * 8, tx0 = (rt - (rt / tw) * tw) * 8;

    const u16* Hbase = Hb + (size_t)n * Hp * Wq * 128;

    // ---- stage halo: 2304 granules of 16B, [gr][row][col]
#pragma unroll
    for (int c = 0; c < 3; ++c) {
        int g = c * 1024 + tid;
        if (c * 1024 + wv * 64 >= 2304) break;
        int gr = g / 144, rem = g - gr * 144;
        int row = rem / 12, col = rem - row * 12;
        int gy = min(max(ty0 - 2 + row, 0), H - 1);
        int gx = min(max(tx0 - 2 + col, 0), W - 1);
        gload16(Hbase + ((size_t)(gy + 1) * Wq + gx + 1) * 128 + gr * 8,
                &halo[(c * 1024 + wv * 64) * 8]);
    }
    // ---- stage om: 512 granules, [q8][p] (waves 0-7)
    if (tid < 512) {
        int q8 = wv, p = lane;
        int gy = min(ty0 + (p >> 3), H - 1);
        int gx = min(tx0 + (p & 7), W - 1);
        gload16((const u16*)(OM + ((size_t)n * HW + gy * W + gx) * 32) + q8 * 8,
                (u16*)oml + (wv * 64) * 8);
    }
    __syncthreads();

    const int p = lane, py = p >> 3, px = p & 7;
    const int y = ty0 + py, x = tx0 + px;
    const bool valid = (y < H) && (x < W);
    const int pixg = n * HW + min(y, H - 1) * W + min(x, W - 1);

#pragma unroll 1
    for (int u = wv; u < 144; u += 16) {
        int k = u >> 4, gr = u & 15;
        if (!valid) continue;
        int gk = k >> 1, ik = (k & 1) * 2;
        float dy = oml[(gk * 64 + p) * 4 + ik];
        float dx = oml[(gk * 64 + p) * 4 + ik + 1];
        int gm = (72 + 4 * k) >> 4, im = ((72 + 4 * k) >> 2) & 3;
        float mm = oml[(gm * 64 + p) * 4 + im];

        float pyf = (float)y - 1.f + (float)(k / 3) + dy;
        float pxf = (float)x - 1.f + (float)(k % 3) + dx;
        float fy = floorf(pyf), fx = floorf(pxf);
        int y0 = (int)fy, x0 = (int)fx;
        float wy = pyf - fy, wx = pxf - fx;
        bool y0v = (y0 >= 0) && (y0 < H), y1v = (y0 >= -1) && (y0 < H - 1);
        bool x0v = (x0 >= 0) && (x0 < W), x1v = (x0 >= -1) && (x0 < W - 1);
        int yc0 = min(max(y0, 0), H - 1), yc1 = min(max(y0 + 1, 0), H - 1);
        int xc0 = min(max(x0, 0), W - 1), xc1 = min(max(x0 + 1, 0), W - 1);
        float w00 = (1.f - wy) * (1.f - wx) * ((y0v && x0v) ? mm : 0.f);
        float w01 = (1.f - wy) * wx         * ((y0v && x1v) ? mm : 0.f);
        float w10 = wy * (1.f - wx)         * ((y1v && x0v) ? mm : 0.f);
        float w11 = wy * wx                 * ((y1v && x1v) ? mm : 0.f);

        int ry0 = yc0 - (ty0 - 2), ry1 = yc1 - (ty0 - 2);
        int rx0 = xc0 - (tx0 - 2), rx1 = xc1 - (tx0 - 2);
        bool allin = (unsigned)ry0 < 12u && (unsigned)ry1 < 12u
                  && (unsigned)rx0 < 12u && (unsigned)rx1 < 12u;
        u16* dst = Acol + ((size_t)(k * 16 + gr) * NHW + pixg) * 8;

        bfrag c00, c01, c10, c11;
        if (allin) {
            int gb = gr * 144 * 8;
            c00 = *(const bfrag*)&halo[gb + (ry0 * 12 + rx0) * 8];
            c01 = *(const bfrag*)&halo[gb + (ry0 * 12 + rx1) * 8];
            c10 = *(const bfrag*)&halo[gb + (ry1 * 12 + rx0) * 8];
            c11 = *(const bfrag*)&halo[gb + (ry1 * 12 + rx1) * 8];
        } else {
            c00 = *(const bfrag*)(Hbase + ((size_t)(yc0 + 1) * Wq + xc0 + 1) * 128 + gr * 8);
            c01 = *(const bfrag*)(Hbase + ((size_t)(yc0 + 1) * Wq + xc1 + 1) * 128 + gr * 8);
            c10 = *(const bfrag*)(Hbase + ((size_t)(yc1 + 1) * Wq + xc0 + 1) * 128 + gr * 8);
            c11 = *(const bfrag*)(Hbase + ((size_t)(yc1 + 1) * Wq + xc1 + 1) * 128 + gr * 8);
        }
        bfrag o;
#pragma unroll
        for (int j = 0; j < 8; ++j) {
            float f = w00 * bf2f((u16)c00[j]) + w01 * bf2f((u16)c01[j])
                    + w10 * bf2f((u16)c10[j]) + w11 * bf2f((u16)c11[j]);
            o[j] = (short)f2bf(f);
        }
        *(bfrag*)dst = o;
    }
}

// =====================================================================
// Dense deform GEMM: M=NHW, N=128, K=10x128. Acol2 layout
// [(tap*16+g)*NHW + pix] granules; tap 9 = residual from padded X.
// MFMA read path identical to verified R6/R7.
// =====================================================================
__global__ __launch_bounds__(512)
void dgemm_k(const u16* __restrict__ Acol, const u16* __restrict__ Xp,
             const u16* __restrict__ Wp, const float* __restrict__ biasC,
             float* __restrict__ T, int H, int W)
{
    __shared__ __align__(16) u16 As[2][64 * 128];          // 32768 B

    const int Hp = H + 2, Wq = W + 2, HW = H * W, NHW = NN * HW;
    const int tid = threadIdx.x, lane = tid & 63, wv = tid >> 6;
    const int wn = wv & 3, wm = wv >> 2;
    const int colc = lane & 15, kg = lane >> 4;
    const int m_base = blockIdx.x * 64;

    const int sg = tid & 15, srow = tid >> 4;
    int pixp[2], gzp[2];
    size_t soffX[2];
#pragma unroll
    for (int pass = 0; pass < 2; ++pass) {
        int r = pass * 32 + srow;
        int pix = m_base + r; if (pix > NHW - 1) pix = NHW - 1;
        int gz = sg ^ (r & 7);
        pixp[pass] = pix; gzp[pass] = gz;
        int n = pix / HW, rr2 = pix - n * HW, y = rr2 / W, x = rr2 - y * W;
        soffX[pass] = ((size_t)(n * Hp + y + 1) * Wq + x + 1) * 128 + gz * 8;
    }

    auto stage = [&](int buf, int tap) {
        if (tap < 9) {
            gload16(Acol + ((size_t)(tap * 16 + gzp[0]) * NHW + pixp[0]) * 8, &As[buf][wv * 512]);
            gload16(Acol + ((size_t)(tap * 16 + gzp[1]) * NHW + pixp[1]) * 8, &As[buf][4096 + wv * 512]);
        } else {
            gload16(Xp + soffX[0], &As[buf][wv * 512]);
            gload16(Xp + soffX[1], &As[buf][4096 + wv * 512]);
        }
    };
    auto wfrag = [&](int tap, int cc, int q) -> const bfrag* {
        return (const bfrag*)(Wp + (size_t)tap * 16384
                              + ((cc * 8 + wn * 2 + q) * 64 + lane) * 8);
    };

    bfrag bc[4][2];
#pragma unroll
    for (int cc = 0; cc < 4; ++cc)
#pragma unroll
        for (int q = 0; q < 2; ++q) bc[cc][q] = *wfrag(0, cc, q);

    facc acc[2][2];
#pragma unroll
    for (int r = 0; r < 2; ++r)
#pragma unroll
        for (int q = 0; q < 2; ++q) acc[r][q] = (facc){0.f, 0.f, 0.f, 0.f};

    stage(0, 0);
    __syncthreads();

#pragma unroll 1
    for (int t = 0; t < 10; ++t) {
        bfrag bn_[4][2];
        if (t < 9) {
#pragma unroll
            for (int cc = 0; cc < 4; ++cc)
#pragma unroll
                for (int q = 0; q < 2; ++q) bn_[cc][q] = *wfrag(t + 1, cc, q);
            stage((t + 1) & 1, t + 1);
        }
        const u16* as = As[t & 1];
#pragma unroll
        for (int cc = 0; cc < 4; ++cc) {
            bfrag a[2];
#pragma unroll
            for (int r = 0; r < 2; ++r) {
                int m = wm * 32 + r * 16 + colc;
                a[r] = *(const bfrag*)&as[m * 128 + ((cc * 4 + kg) ^ (m & 7)) * 8];
            }
#pragma unroll
            for (int r = 0; r < 2; ++r)
#pragma unroll
                for (int q = 0; q < 2; ++q)
                    acc[r][q] = __builtin_amdgcn_mfma_f32_16x16x32_bf16(a[r], bc[cc][q], acc[r][q], 0, 0, 0);
        }
        if (t < 9) {
#pragma unroll
            for (int cc = 0; cc < 4; ++cc)
#pragma unroll
                for (int q = 0; q < 2; ++q) bc[cc][q] = bn_[cc][q];
        }
        __syncthreads();
    }

#pragma unroll
    for (int r = 0; r < 2; ++r) {
#pragma unroll
        for (int j = 0; j < 4; ++j) {
            int pix = m_base + wm * 32 + r * 16 + kg * 4 + j;
            if (pix >= NHW) continue;
#pragma unroll
            for (int q = 0; q < 2; ++q) {
                int oc = wn * 32 + q * 16 + colc;
                T[(size_t)pix * 128 + oc] = fmaxf(acc[r][q][j] + biasC[oc], 0.f);
            }
        }
    }
}

// ---- maxpool 2x2 s1 pad1 (unchanged) -------------------------------------
template<int OUTMODE>
__global__ __launch_bounds__(256)
void pool_k(const float* __restrict__ T, void* __restrict__ Out, int H, int W)
{
    const int HW = H * W, Ho = H + 1, Wo = W + 1;
    int tot = NN * Ho * Wo * 16;
    int idx = blockIdx.x * 256 + threadIdx.x;
    if (idx >= tot) return;
    int cg = idx & 15; int t = idx >> 4;
    int ox = t % Wo; t /= Wo; int oy = t % Ho; int n = t / Ho;

    float mx[8];
#pragma unroll
    for (int j = 0; j < 8; ++j) mx[j] = -INFINITY;
#pragma unroll
    for (int d = 0; d < 2; ++d) {
        int iy = oy - 1 + d;
        if (iy < 0 || iy >= H) continue;
#pragma unroll
        for (int e = 0; e < 2; ++e) {
            int ix = ox - 1 + e;
            if (ix < 0 || ix >= W) continue;
            const float* src = T + ((size_t)(n * HW + iy * W + ix)) * 128 + cg * 8;
#pragma unroll
            for (int j = 0; j < 8; ++j) mx[j] = fmaxf(mx[j], src[j]);
        }
    }
    if constexpr (OUTMODE == 0) {
        int Hp2 = Ho + 2, Wp2 = Wo + 2;
        bfrag o;
#pragma unroll
        for (int j = 0; j < 8; ++j) o[j] = (short)f2bf(mx[j]);
        *(bfrag*)((u16*)Out + ((size_t)(n * Hp2 + oy + 1) * Wp2 + (ox + 1)) * 128 + cg * 8) = o;
    } else {
#pragma unroll
        for (int j = 0; j < 8; ++j) {
            int c = cg * 8 + j;
            ((float*)Out)[(((size_t)n * 128 + c) * Ho + oy) * Wo + ox] = mx[j];
        }
    }
}

// ---- zero the padded buffers ---------------------------------------------
__global__ __launch_bounds__(256)
void prep_k(u16* __restrict__ Xp0, u16* __restrict__ Xp1,
            u16* __restrict__ Hp0, u16* __restrict__ Hp1)
{
    const int G0 = (NN * 66 * 66 * 128) / 8;
    const int G1 = (NN * 67 * 67 * 128) / 8;
    int idx = blockIdx.x * 256 + threadIdx.x;
    bfrag z = (bfrag){0, 0, 0, 0, 0, 0, 0, 0};
    if (idx < G0) { *(bfrag*)(Xp0 + (size_t)idx * 8) = z; return; }
    idx -= G0;
    if (idx < G1) { *(bfrag*)(Xp1 + (size_t)idx * 8) = z; return; }
    idx -= G1;
    if (idx < G0) { *(bfrag*)(Hp0 + (size_t)idx * 8) = z; return; }
    idx -= G0;
    if (idx < G1) { *(bfrag*)(Hp1 + (size_t)idx * 8) = z; return; }
}

// ---- x (NCHW f32) -> padded NHWC bf16 (64x64 -> 66x66) -------------------
__global__ __launch_bounds__(256)
void x0_to_nhwc(const float* __restrict__ x0, u16* __restrict__ Xp)
{
    int idx = blockIdx.x * 256 + threadIdx.x;
    if (idx >= NN * 64 * 64 * 16) return;
    int cg = idx & 15; int t = idx >> 4;
    int x = t & 63; t >>= 6; int y = t & 63; int n = t >> 6;
    bfrag o;
#pragma unroll
    for (int j = 0; j < 8; ++j) {
        int c = cg * 8 + j;
        o[j] = (short)f2bf(x0[(((size_t)n * 128 + c) * 64 + y) * 64 + x]);
    }
    *(bfrag*)(Xp + ((size_t)(n * 66 + y + 1) * 66 + (x + 1)) * 128 + cg * 8) = o;
}

// ---- weight prep (unchanged) ---------------------------------------------
__global__ __launch_bounds__(256)
void wprep_k(const float* __restrict__ w1, const float* __restrict__ b1,
             const float* __restrict__ g1, const float* __restrict__ be1,
             const float* __restrict__ m1, const float* __restrict__ v1,
             const float* __restrict__ w_off, const float* __restrict__ b_off,
             const float* __restrict__ w_mod, const float* __restrict__ b_mod,
             const float* __restrict__ w_def, const float* __restrict__ b_def,
             const float* __restrict__ g2, const float* __restrict__ be2,
             const float* __restrict__ m2, const float* __restrict__ v2,
             const float* __restrict__ w_ds, const float* __restrict__ b_ds,
             const float* __restrict__ g3, const float* __restrict__ be3,
             const float* __restrict__ m3, const float* __restrict__ v3,
             u16* __restrict__ Wb1p, u16* __restrict__ Wbomp, u16* __restrict__ Wbdp,
             float* __restrict__ bias1f, float* __restrict__ biasOM, float* __restrict__ biasC)
{
    const int C1 = 9 * 4 * 8 * 512;   // 147456
    const int C2 = 9 * 4 * 2 * 512;   // 36864
    const int C3 = 10 * 4 * 8 * 512;  // 163840
    int idx = blockIdx.x * 256 + threadIdx.x;
    if (idx < 2 * C1) {
        int inst = idx / C1, e = idx - inst * C1;
        int j = e & 7, lane = (e >> 3) & 63, rest = e >> 9;
        int ob = rest & 7; rest >>= 3; int cc = rest & 3; int tap = rest >> 2;
        int oc = ob * 16 + (lane & 15), c = cc * 32 + (lane >> 4) * 8 + j;
        float sc = g1[inst * 128 + oc] * rsqrtf(v1[inst * 128 + oc] + 1e-5f);
        Wb1p[idx] = f2bf(sc * w1[(((size_t)inst * 128 + oc) * 128 + c) * 9 + tap]);
        return;
    }
    idx -= 2 * C1;
    if (idx < 2 * C2) {
        int inst = idx / C2, e = idx - inst * C2;
        int j = e & 7, lane = (e >> 3) & 63, rest = e >> 9;
        int ob = rest & 1; rest >>= 1; int cc = rest & 3; int tap = rest >> 2;
        int oc = ob * 16 + (lane & 15), c = cc * 32 + (lane >> 4) * 8 + j;
        float v = 0.f;
        if (oc < 18)      v = w_off[(((size_t)inst * 18 + oc) * 128 + c) * 9 + tap];
        else if (oc < 27) v = w_mod[(((size_t)inst * 9 + (oc - 18)) * 128 + c) * 9 + tap];
        Wbomp[inst * C2 + e] = f2bf(v);
        return;
    }
    idx -= 2 * C2;
    if (idx < 2 * C3) {
        int inst = idx / C3, e = idx - inst * C3;
        int j = e & 7, lane = (e >> 3) & 63, rest = e >> 9;
        int ob = rest & 7; rest >>= 3; int cc = rest & 3; int tap = rest >> 2;
        int oc = ob * 16 + (lane & 15), c = cc * 32 + (lane >> 4) * 8 + j;
        float val;
        if (tap < 9) {
            float sc2 = g2[inst * 128 + oc] * rsqrtf(v2[inst * 128 + oc] + 1e-5f);
            val = sc2 * w_def[(((size_t)inst * 128 + oc) * 128 + c) * 9 + tap];
        } else {
            float sc3 = g3[inst * 128 + oc] * rsqrtf(v3[inst * 128 + oc] + 1e-5f);
            val = sc3 * w_ds[((size_t)inst * 128 + oc) * 128 + c];
        }
        Wbdp[inst * C3 + e] = f2bf(val);
        return;
    }
    idx -= 2 * C3;
    if (idx < 2 * 288) {
        int inst = idx / 288, r = idx - inst * 288;
        if (r < 128) {
            int oc = r, o = inst * 128 + oc;
            float sc = g1[o] * rsqrtf(v1[o] + 1e-5f);
            bias1f[o] = sc * b1[o] + be1[o] - m1[o] * sc;
        } else if (r < 160) {
            int oc = r - 128;
            float v = 0.f;
            if (oc < 18)      v = b_off[inst * 18 + oc];
            else if (oc < 27) v = b_mod[inst * 9 + (oc - 18)];
            biasOM[inst * 32 + oc] = v;
        } else {
            int oc = r - 160, o = inst * 128 + oc;
            float sc2 = g2[o] * rsqrtf(v2[o] + 1e-5f);
            float sc3 = g3[o] * rsqrtf(v3[o] + 1e-5f);
            biasC[o] = sc2 * b_def[o] + (be2[o] - m2[o] * sc2)
                     + sc3 * b_ds[o] + (be3[o] - m3[o] * sc3);
        }
    }
}

extern "C" void kernel_launch(void* const* d_in, const int* in_sizes, int n_in,
                              void* d_out, int out_size, void* d_ws, size_t ws_size,
                              hipStream_t stream)
{
    const float* x0    = (const float*)d_in[0];
    const float* w1    = (const float*)d_in[1];
    const float* b1    = (const float*)d_in[2];
    const float* g1    = (const float*)d_in[3];
    const float* be1   = (const float*)d_in[4];
    const float* m1    = (const float*)d_in[5];
    const float* v1    = (const float*)d_in[6];
    const float* w_off = (const float*)d_in[7];
    const float* b_off = (const float*)d_in[8];
    const float* w_mod = (const float*)d_in[9];
    const float* b_mod = (const float*)d_in[10];
    const float* w_def = (const float*)d_in[11];
    const float* b_def = (const float*)d_in[12];
    const float* g2    = (const float*)d_in[13];
    const float* be2   = (const float*)d_in[14];
    const float* m2    = (const float*)d_in[15];
    const float* v2    = (const float*)d_in[16];
    const float* w_ds  = (const float*)d_in[17];
    const float* b_ds  = (const float*)d_in[18];
    const float* g3    = (const float*)d_in[19];
    const float* be3   = (const float*)d_in[20];
    const float* m3    = (const float*)d_in[21];
    const float* v3    = (const float*)d_in[22];

    const int C1 = 147456, C2 = 36864, C3 = 163840;
    char* wsp = (char*)d_ws;
    auto alloc = [&](size_t bytes) { char* r = wsp; wsp += (bytes + 255) & ~(size_t)255; return r; };
    const size_t szX0 = (size_t)NN * 66 * 66 * 128 * 2;
    const size_t szX1 = (size_t)NN * 67 * 67 * 128 * 2;
    u16*   Xpad0  = (u16*)alloc(szX0);
    u16*   Xpad1  = (u16*)alloc(szX1);
    u16*   Hpad0  = (u16*)alloc(szX0);
    u16*   Hpad1  = (u16*)alloc(szX1);
    float* OFFMSK = (float*)alloc((size_t)16900 * 32 * 4);
    float* T      = (float*)alloc((size_t)16900 * 128 * 4);
    u16*   Acol   = (u16*)alloc((size_t)16900 * 1152 * 2);   // [144][NHW] granules
    u16*   Wb1p   = (u16*)alloc((size_t)2 * C1 * 2);
    u16*   Wbomp  = (u16*)alloc((size_t)2 * C2 * 2);
    u16*   Wbdp   = (u16*)alloc((size_t)2 * C3 * 2);
    float* bias1f = (float*)alloc(2 * 128 * 4);
    float* biasOM = (float*)alloc(2 * 32 * 4);
    float* biasC  = (float*)alloc(2 * 128 * 4);

    // ---- prologue: zero pads + layout conversion + weight packing --------
    const int G0 = (NN * 66 * 66 * 128) / 8, G1 = (NN * 67 * 67 * 128) / 8;
    int ztot = 2 * G0 + 2 * G1;
    prep_k<<<(ztot + 255) / 256, 256, 0, stream>>>(Xpad0, Xpad1, Hpad0, Hpad1);
    x0_to_nhwc<<<(NN * 64 * 64 * 16 + 255) / 256, 256, 0, stream>>>(x0, Xpad0);
    int ptot = 2 * C1 + 2 * C2 + 2 * C3 + 2 * 288;
    wprep_k<<<(ptot + 255) / 256, 256, 0, stream>>>(
        w1, b1, g1, be1, m1, v1, w_off, b_off, w_mod, b_mod, w_def, b_def,
        g2, be2, m2, v2, w_ds, b_ds, g3, be3, m3, v3,
        Wb1p, Wbomp, Wbdp, bias1f, biasOM, biasC);

    const u16* curX = Xpad0;
    for (int i = 0; i < 2; ++i) {
        int H = 64 + i, W = 64 + i;
        int HW = H * W;
        int NHW = NN * HW;
        int npb = (HW + 63) / 64;
        int grid = NN * npb;
        u16* Hpad = (i == 0) ? Hpad0 : Hpad1;

        // h = relu(bn1(conv3x3(x)))
        gconv_h<2, 4, 2, 2, 8, 0><<<grid, 512, 0, stream>>>(
            curX, Wb1p + (size_t)i * C1, bias1f + i * 128, Hpad, H, W, npb);
        // off(18) + msk(9, 2*sigmoid) -> OFFMSK [pix][32]
        gconv_h<4, 2, 1, 1, 2, 1><<<grid, 512, 0, stream>>>(
            Hpad, Wbomp + (size_t)i * C2, biasOM + i * 32, OFFMSK, H, W, npb);
        // 2D-tiled LDS bilinear sample (16 waves/block) -> Acol2
        int tw = (W + 7) / 8, th = (H + 7) / 8;
        sample3_k<<<NN * tw * th, 1024, 0, stream>>>(Hpad, OFFMSK, Acol, H, W, tw, th);
        // dense GEMM: 9 sampled taps + residual tap from curX
        dgemm_k<<<(NHW + 63) / 64, 512, 0, stream>>>(
            Acol, curX, Wbdp + (size_t)i * C3, biasC + i * 128, T, H, W);
        // maxpool
        if (i == 0) {
            pool_k<0><<<(NN * 65 * 65 * 16 + 255) / 256, 256, 0, stream>>>(T, Xpad1, H, W);
        } else {
            pool_k<1><<<(NN * 66 * 66 * 16 + 255) / 256, 256, 0, stream>>>(T, d_out, H, W);
        }
        curX = Xpad1;
    }
}

// Round 9
// 139.093 us; speedup vs baseline: 1.2476x; 1.2074x over previous
//
#include <hip/hip_runtime.h>
#include <math.h>

constexpr int NN = 4;    // batch
constexpr int CC = 128;  // channels

typedef unsigned short u16;
typedef short bfrag __attribute__((ext_vector_type(8)));   // 8 bf16
typedef float facc  __attribute__((ext_vector_type(4)));   // 4 f32 acc

__device__ __forceinline__ float bf2f(u16 v) {
    unsigned u = ((unsigned)v) << 16; float f; __builtin_memcpy(&f, &u, 4); return f;
}
__device__ __forceinline__ u16 f2bf(float f) {
    unsigned u; __builtin_memcpy(&u, &f, 4);
    unsigned r = u + 0x7FFFu + ((u >> 16) & 1u);
    return (u16)(r >> 16);
}

typedef const __attribute__((address_space(1))) unsigned int gu32;
typedef __attribute__((address_space(3))) unsigned int lu32;
__device__ __forceinline__ void gload16(const u16* g, u16* l) {
    __builtin_amdgcn_global_load_lds((gu32*)g, (lu32*)l, 16, 0, 0);
}

// =====================================================================
// Halo-LDS 3x3 conv GEMM (unchanged, verified R5-R8).
// =====================================================================
template<int WM, int WN, int MR, int NR, int NOB, int EPI>
__global__ __launch_bounds__(512)
void gconv_h(const u16* __restrict__ A, const u16* __restrict__ Wp,
             const float* __restrict__ bias, void* __restrict__ Out,
             int H, int W, int npb)
{
    constexpr int HALOW = 68;
    __shared__ __align__(16) u16 halo[4 * HALOW * 128];    // 69632 B

    const int Hp = H + 2, Wq = W + 2, HW = H * W;
    const int tid = threadIdx.x, lane = tid & 63, wv = tid >> 6;
    const int wn = wv % WN, wm = wv / WN;
    const int colc = lane & 15, kg = lane >> 4;
    const int n = blockIdx.x / npb;
    const int pib = (blockIdx.x - n * npb) * 64;
    const int ymin = pib / W;

    {
        const u16* Abase = A + (size_t)n * Hp * Wq * 128;
        for (int c = wv; c < 4 * HALOW / 4; c += 8) {
            int o = c * 512 + lane * 8;
            int r = o / (HALOW * 128);
            int e = o - r * (HALOW * 128);
            int x = e >> 7;
            int g = (e >> 3) & 15;
            int xs = x < Wq ? x : Wq - 1;
            int pr = ymin + r; if (pr > Hp - 1) pr = Hp - 1;
            const u16* src = Abase + ((size_t)pr * Wq + xs) * 128 + (g ^ (x & 7)) * 8;
            gload16(src, &halo[c * 512]);
        }
    }
    __syncthreads();

    int dyr[MR], axr[MR];
#pragma unroll
    for (int r = 0; r < MR; ++r) {
        int m = wm * (MR * 16) + r * 16 + colc;
        int pixl = pib + m; if (pixl > HW - 1) pixl = HW - 1;
        int y = pixl / W;
        dyr[r] = y - ymin; axr[r] = pixl - y * W;
    }

    auto wfrag = [&](int tap, int cc, int q) -> const bfrag* {
        return (const bfrag*)(Wp + (size_t)tap * (NOB * 2048)
                              + ((cc * NOB + wn * NR + q) * 64 + lane) * 8);
    };

    bfrag bc[4][NR];
#pragma unroll
    for (int cc = 0; cc < 4; ++cc)
#pragma unroll
        for (int q = 0; q < NR; ++q) bc[cc][q] = *wfrag(0, cc, q);

    facc acc[MR][NR];
#pragma unroll
    for (int r = 0; r < MR; ++r)
#pragma unroll
        for (int q = 0; q < NR; ++q) acc[r][q] = (facc){0.f, 0.f, 0.f, 0.f};

#pragma unroll 1
    for (int t = 0; t < 9; ++t) {
        int ty = t / 3, tx = t - ty * 3;
        bfrag bn_[4][NR];
        if (t < 8) {
#pragma unroll
            for (int cc = 0; cc < 4; ++cc)
#pragma unroll
                for (int q = 0; q < NR; ++q) bn_[cc][q] = *wfrag(t + 1, cc, q);
        }
#pragma unroll
        for (int cc = 0; cc < 4; ++cc) {
            bfrag a[MR];
#pragma unroll
            for (int r = 0; r < MR; ++r) {
                int xx = axr[r] + tx;
                a[r] = *(const bfrag*)&halo[((dyr[r] + ty) * HALOW + xx) * 128
                                            + ((cc * 4 + kg) ^ (xx & 7)) * 8];
            }
#pragma unroll
            for (int r = 0; r < MR; ++r)
#pragma unroll
                for (int q = 0; q < NR; ++q)
                    acc[r][q] = __builtin_amdgcn_mfma_f32_16x16x32_bf16(a[r], bc[cc][q], acc[r][q], 0, 0, 0);
        }
        if (t < 8) {
#pragma unroll
            for (int cc = 0; cc < 4; ++cc)
#pragma unroll
                for (int q = 0; q < NR; ++q) bc[cc][q] = bn_[cc][q];
        }
    }

#pragma unroll
    for (int r = 0; r < MR; ++r) {
#pragma unroll
        for (int j = 0; j < 4; ++j) {
            int m = wm * (MR * 16) + r * 16 + kg * 4 + j;
            int pixl = pib + m;
            if (pixl >= HW) continue;
#pragma unroll
            for (int q = 0; q < NR; ++q) {
                int oc = wn * (NR * 16) + q * 16 + colc;
                float val = acc[r][q][j] + bias[oc];
                if constexpr (EPI == 0) {
                    val = fmaxf(val, 0.f);
                    int y = pixl / W, x = pixl - y * W;
                    ((u16*)Out)[((size_t)(n * Hp + y + 1) * Wq + x + 1) * 128 + oc] = f2bf(val);
                } else {
                    if (oc >= 18) val = 2.f / (1.f + expf(-val));
                    ((float*)Out)[((size_t)n * HW + pixl) * 32 + oc] = val;
                }
            }
        }
    }
}

// =====================================================================
// Fused deformable conv v2. Block = 8x4 pixel tile (BM=32), 8 waves.
// LDS: 8x12 halo in [slot][granule^slot] (conflict-free corner reads,
// 24.5KB) + OM slice [pix][32] (4KB) + As dbuf (16KB) = 45KB ->
// 2 blocks/CU, 4 waves/SIMD. Fully unrolled 10-tap loop: per tap
// {1 sample/thread from LDS -> swizzled As} || {8 MFMA/wave, B from L2};
// tap 9 = residual from padded X via pre-swizzled gload16.
// Out-of-window corners (rare) fall back to global -> exact any offset.
// =====================================================================
__global__ __launch_bounds__(512, 4)
void deform2_k(const u16* __restrict__ Hb, const u16* __restrict__ Xp,
               const float* __restrict__ OM, const u16* __restrict__ Wp,
               const float* __restrict__ biasC, float* __restrict__ T,
               int H, int W, int tw, int th)
{
    __shared__ __align__(16) u16 halo[96 * 16 * 8];    // 24576 B
    __shared__ __align__(16) float oml[32 * 32];       // 4096 B
    __shared__ __align__(16) u16 As2[2][32 * 128];     // 16384 B

    const int Hp = H + 2, Wq = W + 2, HW = H * W;
    const int tid = threadIdx.x, lane = tid & 63, wv = tid >> 6;
    const int wn = wv & 3, wm = wv >> 2;               // wave tile 16px x 32oc
    const int colc = lane & 15, kg = lane >> 4;
    int bt = blockIdx.x;
    int n = bt / (tw * th); int rt = bt - n * (tw * th);
    int ty0 = (rt / tw) * 4, tx0 = (rt - (rt / tw) * tw) * 8;
    const u16* Hbase = Hb + (size_t)n * Hp * Wq * 128;

    // ---- stage halo: 8 rows x 12 cols x 16 granules, slot-swizzled
#pragma unroll
    for (int c = 0; c < 3; ++c) {
        int g = c * 512 + tid;
        int s = g >> 4, u = g & 15;
        int row = s / 12, col = s - row * 12;
        int gy = min(max(ty0 - 2 + row, 0), H - 1);
        int gx = min(max(tx0 - 2 + col, 0), W - 1);
        int gr = u ^ (s & 15);
        gload16(Hbase + ((size_t)(gy + 1) * Wq + gx + 1) * 128 + gr * 8,
                &halo[(c * 512 + wv * 64) * 8]);
    }
    // ---- stage om: 32 px x 32 f = 256 granules (waves 0-3), [pix][32]
    if (tid < 256) {
        int r = tid >> 3, q4 = tid & 7;
        int yy = min(ty0 + (r >> 3), H - 1), xx = min(tx0 + (r & 7), W - 1);
        gload16((const u16*)(OM + ((size_t)n * HW + yy * W + xx) * 32) + q4 * 8,
                (u16*)oml + wv * 64 * 8);
    }

    const int sg = tid & 15, srow = tid >> 4;
    const int sgz = sg ^ (srow & 7);
    const int cy = min(ty0 + (srow >> 3), H - 1), cx = min(tx0 + (srow & 7), W - 1);
    const size_t soffX = ((size_t)(n * Hp + cy + 1) * Wq + cx + 1) * 128 + sgz * 8;
    __syncthreads();

    auto sample = [&](int buf, int k) {
        int ky = k / 3, kx = k - ky * 3;
        float dy = oml[srow * 32 + 2 * k];
        float dx = oml[srow * 32 + 2 * k + 1];
        float mm = oml[srow * 32 + 18 + k];
        float pyf = (float)cy - 1.f + (float)ky + dy;
        float pxf = (float)cx - 1.f + (float)kx + dx;
        float fy = floorf(pyf), fx = floorf(pxf);
        int y0 = (int)fy, x0 = (int)fx;
        float wy = pyf - fy, wx = pxf - fx;
        bool y0v = (y0 >= 0) && (y0 < H), y1v = (y0 >= -1) && (y0 < H - 1);
        bool x0v = (x0 >= 0) && (x0 < W), x1v = (x0 >= -1) && (x0 < W - 1);
        int yc0 = min(max(y0, 0), H - 1), yc1 = min(max(y0 + 1, 0), H - 1);
        int xc0 = min(max(x0, 0), W - 1), xc1 = min(max(x0 + 1, 0), W - 1);
        float w00 = (1.f - wy) * (1.f - wx) * ((y0v && x0v) ? mm : 0.f);
        float w01 = (1.f - wy) * wx         * ((y0v && x1v) ? mm : 0.f);
        float w10 = wy * (1.f - wx)         * ((y1v && x0v) ? mm : 0.f);
        float w11 = wy * wx                 * ((y1v && x1v) ? mm : 0.f);
        int ry0 = yc0 - ty0 + 2, ry1 = yc1 - ty0 + 2;
        int rx0 = xc0 - tx0 + 2, rx1 = xc1 - tx0 + 2;
        bool allin = (unsigned)ry0 < 8u && (unsigned)ry1 < 8u
                  && (unsigned)rx0 < 12u && (unsigned)rx1 < 12u;
        bfrag c00, c01, c10, c11;
        if (allin) {
            int s00 = ry0 * 12 + rx0, s01 = ry0 * 12 + rx1;
            int s10 = ry1 * 12 + rx0, s11 = ry1 * 12 + rx1;
            c00 = *(const bfrag*)&halo[(s00 * 16 + (sg ^ (s00 & 15))) * 8];
            c01 = *(const bfrag*)&halo[(s01 * 16 + (sg ^ (s01 & 15))) * 8];
            c10 = *(const bfrag*)&halo[(s10 * 16 + (sg ^ (s10 & 15))) * 8];
            c11 = *(const bfrag*)&halo[(s11 * 16 + (sg ^ (s11 & 15))) * 8];
        } else {
            c00 = *(const bfrag*)(Hbase + ((size_t)(yc0 + 1) * Wq + xc0 + 1) * 128 + sg * 8);
            c01 = *(const bfrag*)(Hbase + ((size_t)(yc0 + 1) * Wq + xc1 + 1) * 128 + sg * 8);
            c10 = *(const bfrag*)(Hbase + ((size_t)(yc1 + 1) * Wq + xc0 + 1) * 128 + sg * 8);
            c11 = *(const bfrag*)(Hbase + ((size_t)(yc1 + 1) * Wq + xc1 + 1) * 128 + sg * 8);
        }
        bfrag o;
#pragma unroll
        for (int j = 0; j < 8; ++j) {
            float f = w00 * bf2f((u16)c00[j]) + w01 * bf2f((u16)c01[j])
                    + w10 * bf2f((u16)c10[j]) + w11 * bf2f((u16)c11[j]);
            o[j] = (short)f2bf(f);
        }
        *(bfrag*)&As2[buf][srow * 128 + sgz * 8] = o;
    };

    facc acc[2];
    acc[0] = (facc){0.f, 0.f, 0.f, 0.f};
    acc[1] = (facc){0.f, 0.f, 0.f, 0.f};

    sample(0, 0);
    __syncthreads();

#pragma unroll
    for (int t = 0; t < 10; ++t) {
        if (t < 8)       sample((t + 1) & 1, t + 1);
        else if (t == 8) gload16(Xp + soffX, &As2[1][wv * 512]);
        const u16* as = As2[t & 1];
        const int m = wm * 16 + colc;
#pragma unroll
        for (int cc = 0; cc < 4; ++cc) {
            bfrag a = *(const bfrag*)&as[m * 128 + ((cc * 4 + kg) ^ (m & 7)) * 8];
#pragma unroll
            for (int q = 0; q < 2; ++q) {
                bfrag b = *(const bfrag*)(Wp + (size_t)t * 16384
                            + ((cc * 8 + wn * 2 + q) * 64 + lane) * 8);
                acc[q] = __builtin_amdgcn_mfma_f32_16x16x32_bf16(a, b, acc[q], 0, 0, 0);
            }
        }
        __syncthreads();
    }

#pragma unroll
    for (int j = 0; j < 4; ++j) {
        int m = wm * 16 + kg * 4 + j;
        int y = ty0 + (m >> 3), x = tx0 + (m & 7);
        if (y >= H || x >= W) continue;
#pragma unroll
        for (int q = 0; q < 2; ++q) {
            int oc = wn * 32 + q * 16 + colc;
            T[((size_t)n * HW + y * W + x) * 128 + oc] = fmaxf(acc[q][j] + biasC[oc], 0.f);
        }
    }
}

// ---- maxpool 2x2 s1 pad1 (unchanged) -------------------------------------
template<int OUTMODE>
__global__ __launch_bounds__(256)
void pool_k(const float* __restrict__ T, void* __restrict__ Out, int H, int W)
{
    const int HW = H * W, Ho = H + 1, Wo = W + 1;
    int tot = NN * Ho * Wo * 16;
    int idx = blockIdx.x * 256 + threadIdx.x;
    if (idx >= tot) return;
    int cg = idx & 15; int t = idx >> 4;
    int ox = t % Wo; t /= Wo; int oy = t % Ho; int n = t / Ho;

    float mx[8];
#pragma unroll
    for (int j = 0; j < 8; ++j) mx[j] = -INFINITY;
#pragma unroll
    for (int d = 0; d < 2; ++d) {
        int iy = oy - 1 + d;
        if (iy < 0 || iy >= H) continue;
#pragma unroll
        for (int e = 0; e < 2; ++e) {
            int ix = ox - 1 + e;
            if (ix < 0 || ix >= W) continue;
            const float* src = T + ((size_t)(n * HW + iy * W + ix)) * 128 + cg * 8;
#pragma unroll
            for (int j = 0; j < 8; ++j) mx[j] = fmaxf(mx[j], src[j]);
        }
    }
    if constexpr (OUTMODE == 0) {
        int Hp2 = Ho + 2, Wp2 = Wo + 2;
        bfrag o;
#pragma unroll
        for (int j = 0; j < 8; ++j) o[j] = (short)f2bf(mx[j]);
        *(bfrag*)((u16*)Out + ((size_t)(n * Hp2 + oy + 1) * Wp2 + (ox + 1)) * 128 + cg * 8) = o;
    } else {
#pragma unroll
        for (int j = 0; j < 8; ++j) {
            int c = cg * 8 + j;
            ((float*)Out)[(((size_t)n * 128 + c) * Ho + oy) * Wo + ox] = mx[j];
        }
    }
}

// ---- zero the padded buffers ---------------------------------------------
__global__ __launch_bounds__(256)
void prep_k(u16* __restrict__ Xp0, u16* __restrict__ Xp1,
            u16* __restrict__ Hp0, u16* __restrict__ Hp1)
{
    const int G0 = (NN * 66 * 66 * 128) / 8;
    const int G1 = (NN * 67 * 67 * 128) / 8;
    int idx = blockIdx.x * 256 + threadIdx.x;
    bfrag z = (bfrag){0, 0, 0, 0, 0, 0, 0, 0};
    if (idx < G0) { *(bfrag*)(Xp0 + (size_t)idx * 8) = z; return; }
    idx -= G0;
    if (idx < G1) { *(bfrag*)(Xp1 + (size_t)idx * 8) = z; return; }
    idx -= G1;
    if (idx < G0) { *(bfrag*)(Hp0 + (size_t)idx * 8) = z; return; }
    idx -= G0;
    if (idx < G1) { *(bfrag*)(Hp1 + (size_t)idx * 8) = z; return; }
}

// ---- x (NCHW f32) -> padded NHWC bf16 (64x64 -> 66x66) -------------------
__global__ __launch_bounds__(256)
void x0_to_nhwc(const float* __restrict__ x0, u16* __restrict__ Xp)
{
    int idx = blockIdx.x * 256 + threadIdx.x;
    if (idx >= NN * 64 * 64 * 16) return;
    int cg = idx & 15; int t = idx >> 4;
    int x = t & 63; t >>= 6; int y = t & 63; int n = t >> 6;
    bfrag o;
#pragma unroll
    for (int j = 0; j < 8; ++j) {
        int c = cg * 8 + j;
        o[j] = (short)f2bf(x0[(((size_t)n * 128 + c) * 64 + y) * 64 + x]);
    }
    *(bfrag*)(Xp + ((size_t)(n * 66 + y + 1) * 66 + (x + 1)) * 128 + cg * 8) = o;
}

// ---- weight prep (unchanged) ---------------------------------------------
__global__ __launch_bounds__(256)
void wprep_k(const float* __restrict__ w1, const float* __restrict__ b1,
             const float* __restrict__ g1, const float* __restrict__ be1,
             const float* __restrict__ m1, const float* __restrict__ v1,
             const float* __restrict__ w_off, const float* __restrict__ b_off,
             const float* __restrict__ w_mod, const float* __restrict__ b_mod,
             const float* __restrict__ w_def, const float* __restrict__ b_def,
             const float* __restrict__ g2, const float* __restrict__ be2,
             const float* __restrict__ m2, const float* __restrict__ v2,
             const float* __restrict__ w_ds, const float* __restrict__ b_ds,
             const float* __restrict__ g3, const float* __restrict__ be3,
             const float* __restrict__ m3, const float* __restrict__ v3,
             u16* __restrict__ Wb1p, u16* __restrict__ Wbomp, u16* __restrict__ Wbdp,
             float* __restrict__ bias1f, float* __restrict__ biasOM, float* __restrict__ biasC)
{
    const int C1 = 9 * 4 * 8 * 512;   // 147456
    const int C2 = 9 * 4 * 2 * 512;   // 36864
    const int C3 = 10 * 4 * 8 * 512;  // 163840
    int idx = blockIdx.x * 256 + threadIdx.x;
    if (idx < 2 * C1) {
        int inst = idx / C1, e = idx - inst * C1;
        int j = e & 7, lane = (e >> 3) & 63, rest = e >> 9;
        int ob = rest & 7; rest >>= 3; int cc = rest & 3; int tap = rest >> 2;
        int oc = ob * 16 + (lane & 15), c = cc * 32 + (lane >> 4) * 8 + j;
        float sc = g1[inst * 128 + oc] * rsqrtf(v1[inst * 128 + oc] + 1e-5f);
        Wb1p[idx] = f2bf(sc * w1[(((size_t)inst * 128 + oc) * 128 + c) * 9 + tap]);
        return;
    }
    idx -= 2 * C1;
    if (idx < 2 * C2) {
        int inst = idx / C2, e = idx - inst * C2;
        int j = e & 7, lane = (e >> 3) & 63, rest = e >> 9;
        int ob = rest & 1; rest >>= 1; int cc = rest & 3; int tap = rest >> 2;
        int oc = ob * 16 + (lane & 15), c = cc * 32 + (lane >> 4) * 8 + j;
        float v = 0.f;
        if (oc < 18)      v = w_off[(((size_t)inst * 18 + oc) * 128 + c) * 9 + tap];
        else if (oc < 27) v = w_mod[(((size_t)inst * 9 + (oc - 18)) * 128 + c) * 9 + tap];
        Wbomp[inst * C2 + e] = f2bf(v);
        return;
    }
    idx -= 2 * C2;
    if (idx < 2 * C3) {
        int inst = idx / C3, e = idx - inst * C3;
        int j = e & 7, lane = (e >> 3) & 63, rest = e >> 9;
        int ob = rest & 7; rest >>= 3; int cc = rest & 3; int tap = rest >> 2;
        int oc = ob * 16 + (lane & 15), c = cc * 32 + (lane >> 4) * 8 + j;
        float val;
        if (tap < 9) {
            float sc2 = g2[inst * 128 + oc] * rsqrtf(v2[inst * 128 + oc] + 1e-5f);
            val = sc2 * w_def[(((size_t)inst * 128 + oc) * 128 + c) * 9 + tap];
        } else {
            float sc3 = g3[inst * 128 + oc] * rsqrtf(v3[inst * 128 + oc] + 1e-5f);
            val = sc3 * w_ds[((size_t)inst * 128 + oc) * 128 + c];
        }
        Wbdp[inst * C3 + e] = f2bf(val);
        return;
    }
    idx -= 2 * C3;
    if (idx < 2 * 288) {
        int inst = idx / 288, r = idx - inst * 288;
        if (r < 128) {
            int oc = r, o = inst * 128 + oc;
            float sc = g1[o] * rsqrtf(v1[o] + 1e-5f);
            bias1f[o] = sc * b1[o] + be1[o] - m1[o] * sc;
        } else if (r < 160) {
            int oc = r - 128;
            float v = 0.f;
            if (oc < 18)      v = b_off[inst * 18 + oc];
            else if (oc < 27) v = b_mod[inst * 9 + (oc - 18)];
            biasOM[inst * 32 + oc] = v;
        } else {
            int oc = r - 160, o = inst * 128 + oc;
            float sc2 = g2[o] * rsqrtf(v2[o] + 1e-5f);
            float sc3 = g3[o] * rsqrtf(v3[o] + 1e-5f);
            biasC[o] = sc2 * b_def[o] + (be2[o] - m2[o] * sc2)
                     + sc3 * b_ds[o] + (be3[o] - m3[o] * sc3);
        }
    }
}

extern "C" void kernel_launch(void* const* d_in, const int* in_sizes, int n_in,
                              void* d_out, int out_size, void* d_ws, size_t ws_size,
                              hipStream_t stream)
{
    const float* x0    = (const float*)d_in[0];
    const float* w1    = (const float*)d_in[1];
    const float* b1    = (const float*)d_in[2];
    const float* g1    = (const float*)d_in[3];
    const float* be1   = (const float*)d_in[4];
    const float* m1    = (const float*)d_in[5];
    const float* v1    = (const float*)d_in[6];
    const float* w_off = (const float*)d_in[7];
    const float* b_off = (const float*)d_in[8];
    const float* w_mod = (const float*)d_in[9];
    const float* b_mod = (const float*)d_in[10];
    const float* w_def = (const float*)d_in[11];
    const float* b_def = (const float*)d_in[12];
    const float* g2    = (const float*)d_in[13];
    const float* be2   = (const float*)d_in[14];
    const float* m2    = (const float*)d_in[15];
    const float* v2    = (const float*)d_in[16];
    const float* w_ds  = (const float*)d_in[17];
    const float* b_ds  = (const float*)d_in[18];
    const float* g3    = (const float*)d_in[19];
    const float* be3   = (const float*)d_in[20];
    const float* m3    = (const float*)d_in[21];
    const float* v3    = (const float*)d_in[22];

    const int C1 = 147456, C2 = 36864, C3 = 163840;
    char* wsp = (char*)d_ws;
    auto alloc = [&](size_t bytes) { char* r = wsp; wsp += (bytes + 255) & ~(size_t)255; return r; };
    const size_t szX0 = (size_t)NN * 66 * 66 * 128 * 2;
    const size_t szX1 = (size_t)NN * 67 * 67 * 128 * 2;
    u16*   Xpad0  = (u16*)alloc(szX0);
    u16*   Xpad1  = (u16*)alloc(szX1);
    u16*   Hpad0  = (u16*)alloc(szX0);
    u16*   Hpad1  = (u16*)alloc(szX1);
    float* OFFMSK = (float*)alloc((size_t)16900 * 32 * 4);
    float* T      = (float*)alloc((size_t)16900 * 128 * 4);
    u16*   Wb1p   = (u16*)alloc((size_t)2 * C1 * 2);
    u16*   Wbomp  = (u16*)alloc((size_t)2 * C2 * 2);
    u16*   Wbdp   = (u16*)alloc((size_t)2 * C3 * 2);
    float* bias1f = (float*)alloc(2 * 128 * 4);
    float* biasOM = (float*)alloc(2 * 32 * 4);
    float* biasC  = (float*)alloc(2 * 128 * 4);

    // ---- prologue: zero pads + layout conversion + weight packing --------
    const int G0 = (NN * 66 * 66 * 128) / 8, G1 = (NN * 67 * 67 * 128) / 8;
    int ztot = 2 * G0 + 2 * G1;
    prep_k<<<(ztot + 255) / 256, 256, 0, stream>>>(Xpad0, Xpad1, Hpad0, Hpad1);
    x0_to_nhwc<<<(NN * 64 * 64 * 16 + 255) / 256, 256, 0, stream>>>(x0, Xpad0);
    int ptot = 2 * C1 + 2 * C2 + 2 * C3 + 2 * 288;
    wprep_k<<<(ptot + 255) / 256, 256, 0, stream>>>(
        w1, b1, g1, be1, m1, v1, w_off, b_off, w_mod, b_mod, w_def, b_def,
        g2, be2, m2, v2, w_ds, b_ds, g3, be3, m3, v3,
        Wb1p, Wbomp, Wbdp, bias1f, biasOM, biasC);

    const u16* curX = Xpad0;
    for (int i = 0; i < 2; ++i) {
        int H = 64 + i, W = 64 + i;
        int HW = H * W;
        int npb = (HW + 63) / 64;
        int grid = NN * npb;
        u16* Hpad = (i == 0) ? Hpad0 : Hpad1;

        // h = relu(bn1(conv3x3(x)))
        gconv_h<2, 4, 2, 2, 8, 0><<<grid, 512, 0, stream>>>(
            curX, Wb1p + (size_t)i * C1, bias1f + i * 128, Hpad, H, W, npb);
        // off(18) + msk(9, 2*sigmoid) -> OFFMSK [pix][32]
        gconv_h<4, 2, 1, 1, 2, 1><<<grid, 512, 0, stream>>>(
            Hpad, Wbomp + (size_t)i * C2, biasOM + i * 32, OFFMSK, H, W, npb);
        // fused deformable conv + residual + bn2/bn3 + relu
        int tw = (W + 7) / 8, th = (H + 3) / 4;
        deform2_k<<<NN * tw * th, 512, 0, stream>>>(
            Hpad, curX, OFFMSK, Wbdp + (size_t)i * C3, biasC + i * 128, T, H, W, tw, th);
        // maxpool
        if (i == 0) {
            pool_k<0><<<(NN * 65 * 65 * 16 + 255) / 256, 256, 0, stream>>>(T, Xpad1, H, W);
        } else {
            pool_k<1><<<(NN * 66 * 66 * 16 + 255) / 256, 256, 0, stream>>>(T, d_out, H, W);
        }
        curX = Xpad1;
    }
}